// Round 1
// 281.709 us; speedup vs baseline: 1.1577x; 1.1577x over previous
//
#include <hip/hip_runtime.h>
#include <math.h>

#define BB 8
#define NN 2048
#define DD 256
#define KK 100
#define RR 5
#define BIGV 1000000000.0f
#define LN_EPS 1e-5f

typedef __attribute__((ext_vector_type(8))) short short8;
typedef __attribute__((ext_vector_type(4))) float floatx4;

// ---------------------------------------------------------------------------
// bf16 helpers (manual RNE to avoid header API variance)
// ---------------------------------------------------------------------------
__device__ static inline unsigned short f2bf_rne(float x) {
  unsigned int u = __float_as_uint(x);
  unsigned int r = (u + 0x7FFFu + ((u >> 16) & 1u)) >> 16;
  return (unsigned short)r;
}
__device__ static inline float bf2f(unsigned short h) {
  return __uint_as_float(((unsigned int)h) << 16);
}

__device__ static inline void gl_lds16(const unsigned short* g, unsigned short* l) {
  __builtin_amdgcn_global_load_lds(
      (const __attribute__((address_space(1))) unsigned int*)(g),
      (__attribute__((address_space(3))) unsigned int*)(l), 16, 0, 0);
}

// ---------------------------------------------------------------------------
// Kernel 0: split q,k (fp32) into bf16 hi/lo planes. hi = RNE(x), lo = RNE(x-hi).
// ---------------------------------------------------------------------------
__global__ __launch_bounds__(256) void split_bf16(const float* __restrict__ q,
                                                  const float* __restrict__ k,
                                                  ushort4* __restrict__ qhi,
                                                  ushort4* __restrict__ qlo,
                                                  ushort4* __restrict__ khi,
                                                  ushort4* __restrict__ klo) {
  const int n4 = BB * NN * DD / 4;
  const float4* src = (blockIdx.y == 0) ? (const float4*)q : (const float4*)k;
  ushort4* hi = blockIdx.y ? khi : qhi;
  ushort4* lo = blockIdx.y ? klo : qlo;
  for (int i = blockIdx.x * 256 + threadIdx.x; i < n4; i += gridDim.x * 256) {
    float4 v = src[i];
    ushort4 h, l;
    h.x = f2bf_rne(v.x); l.x = f2bf_rne(v.x - bf2f(h.x));
    h.y = f2bf_rne(v.y); l.y = f2bf_rne(v.y - bf2f(h.y));
    h.z = f2bf_rne(v.z); l.z = f2bf_rne(v.z - bf2f(h.z));
    h.w = f2bf_rne(v.w); l.w = f2bf_rne(v.w - bf2f(h.w));
    hi[i] = h; lo[i] = l;
  }
}

// ---------------------------------------------------------------------------
// Kernel 1: logits via MFMA with 3-term bf16 split.
// 128x128 tile per block, 4 waves (2x2 of 64x64), BK=32, 16x16x32 bf16 MFMA.
// v2: double-buffered LDS (2x32 KiB) + raw s_barrier + counted vmcnt(8) so
// stage t+1's global_load_lds stay in flight across step t's compute
// (T3/T4 minimum pipeline — avoids the compiler's vmcnt(0) drain at
// __syncthreads that exposed one HBM round-trip per K-step).
// XCD swizzle: 2048 blocks, XCD c <- batch c (4 MB of planes fits 4 MB L2).
// ---------------------------------------------------------------------------
__global__ __launch_bounds__(256) void gemm_mfma_split(
    const unsigned short* __restrict__ qhi, const unsigned short* __restrict__ qlo,
    const unsigned short* __restrict__ khi, const unsigned short* __restrict__ klo,
    float* __restrict__ s) {
  __shared__ unsigned short lds[2][4][8][512];  // 64 KiB, double-buffered

  // grid = (16,16,8) -> 2048 blocks, nwg % 8 == 0 so swizzle is bijective
  const int lid = blockIdx.x + ((blockIdx.y + (blockIdx.z << 4)) << 4);
  const int swz = ((lid & 7) << 8) + (lid >> 3);
  const int bx = swz & 15;
  const int by = (swz >> 4) & 15;
  const int b = swz >> 8;
  const int i0 = by * 128, j0 = bx * 128;

  const int t = threadIdx.x;
  const int w = t >> 6, L = t & 63;
  const int wx = w & 1, wy = w >> 1;
  const int q_ = L >> 4, m_ = L & 15;

  const size_t bofs = (size_t)b * NN * DD;
  const unsigned short* base;
  {
    const unsigned short* b0 = qhi + bofs;
    const unsigned short* b1 = qlo + bofs;
    const unsigned short* b2 = khi + bofs;
    const unsigned short* b3 = klo + bofs;
    base = (w == 0) ? b0 : (w == 1) ? b1 : (w == 2) ? b2 : b3;
  }
  const int rowbase = (w < 2 ? i0 : j0);
  // per-lane global base: row (rowbase + r*16 + m_), col (kb0 + q_*8)
  const unsigned short* gbase = base + (size_t)(rowbase + m_) * DD + q_ * 8;

  floatx4 acc[4][4];
#pragma unroll
  for (int i = 0; i < 4; ++i)
#pragma unroll
    for (int j = 0; j < 4; ++j) acc[i][j] = (floatx4){0.f, 0.f, 0.f, 0.f};

#define STAGE(buf, kb0)                                              \
  _Pragma("unroll") for (int r = 0; r < 8; ++r)                      \
      gl_lds16(gbase + (size_t)r * 16 * DD + (kb0), &lds[buf][w][r][0]);

  STAGE(0, 0);
  int cur = 0;
#pragma unroll
  for (int it = 0; it < 8; ++it) {
    if (it < 7) {
      STAGE(cur ^ 1, (it + 1) * 32);
      // wait only for stage `it`'s 8 loads; stage it+1's 8 stay in flight
      asm volatile("s_waitcnt vmcnt(8)" ::: "memory");
    } else {
      asm volatile("s_waitcnt vmcnt(0)" ::: "memory");
    }
    __builtin_amdgcn_s_barrier();

    short8 ah[4], al[4], bh[4], bl[4];
#pragma unroll
    for (int i = 0; i < 4; ++i) {
      ah[i] = *(const short8*)&lds[cur][0][wy * 4 + i][L * 8];
      al[i] = *(const short8*)&lds[cur][1][wy * 4 + i][L * 8];
      bh[i] = *(const short8*)&lds[cur][2][wx * 4 + i][L * 8];
      bl[i] = *(const short8*)&lds[cur][3][wx * 4 + i][L * 8];
    }
#pragma unroll
    for (int i = 0; i < 4; ++i)
#pragma unroll
      for (int j = 0; j < 4; ++j) {
        acc[i][j] = __builtin_amdgcn_mfma_f32_16x16x32_bf16(ah[i], bh[j], acc[i][j], 0, 0, 0);
        acc[i][j] = __builtin_amdgcn_mfma_f32_16x16x32_bf16(ah[i], bl[j], acc[i][j], 0, 0, 0);
        acc[i][j] = __builtin_amdgcn_mfma_f32_16x16x32_bf16(al[i], bh[j], acc[i][j], 0, 0, 0);
      }
    // all ds_reads of buf[cur] were consumed by the MFMAs above (lgkmcnt
    // inserted by compiler), so after this barrier buf[cur] may be restaged.
    __builtin_amdgcn_s_barrier();
    cur ^= 1;
  }
#undef STAGE

  // C/D layout (m89-verified): col = lane&15, row = (lane>>4)*4 + reg
#pragma unroll
  for (int i = 0; i < 4; ++i)
#pragma unroll
    for (int j = 0; j < 4; ++j)
#pragma unroll
      for (int r = 0; r < 4; ++r) {
        int row = i0 + wy * 64 + i * 16 + q_ * 4 + r;
        int col = j0 + wx * 64 + j * 16 + m_;
        s[((size_t)b * NN + row) * NN + col] = acc[i][j][r];
      }
}

// ---------------------------------------------------------------------------
// Kernel 1-fallback: fp32 vector GEMM (used only if ws too small for splits).
// ---------------------------------------------------------------------------
__global__ __launch_bounds__(256) void gemm_logits(const float* __restrict__ q,
                                                   const float* __restrict__ k,
                                                   float* __restrict__ s) {
  __shared__ float As[32][132];
  __shared__ float Bs[32][132];
  const int b = blockIdx.z;
  const int i0 = blockIdx.y * 128;
  const int j0 = blockIdx.x * 128;
  const int t = threadIdx.x;
  const int tx = t & 15;
  const int ty = t >> 4;
  const float* qb = q + (size_t)b * NN * DD;
  const float* kb = k + (size_t)b * NN * DD;

  float acc[8][8];
#pragma unroll
  for (int i = 0; i < 8; ++i)
#pragma unroll
    for (int j = 0; j < 8; ++j) acc[i][j] = 0.f;

  for (int kb0 = 0; kb0 < DD; kb0 += 32) {
#pragma unroll
    for (int l = 0; l < 4; ++l) {
      int f = l * 256 + t;
      int row = f >> 3;
      int c4 = (f & 7) * 4;
      float4 va = *(const float4*)(qb + (size_t)(i0 + row) * DD + kb0 + c4);
      float4 vb = *(const float4*)(kb + (size_t)(j0 + row) * DD + kb0 + c4);
      As[c4 + 0][row] = va.x; As[c4 + 1][row] = va.y;
      As[c4 + 2][row] = va.z; As[c4 + 3][row] = va.w;
      Bs[c4 + 0][row] = vb.x; Bs[c4 + 1][row] = vb.y;
      Bs[c4 + 2][row] = vb.z; Bs[c4 + 3][row] = vb.w;
    }
    __syncthreads();
#pragma unroll
    for (int kk = 0; kk < 32; ++kk) {
      float a[8], bv[8];
      *(float4*)&a[0] = *(const float4*)&As[kk][ty * 8];
      *(float4*)&a[4] = *(const float4*)&As[kk][ty * 8 + 4];
      *(float4*)&bv[0] = *(const float4*)&Bs[kk][tx * 8];
      *(float4*)&bv[4] = *(const float4*)&Bs[kk][tx * 8 + 4];
#pragma unroll
      for (int i = 0; i < 8; ++i)
#pragma unroll
        for (int j = 0; j < 8; ++j) acc[i][j] += a[i] * bv[j];
    }
    __syncthreads();
  }

#pragma unroll
  for (int i = 0; i < 8; ++i) {
    size_t row = (size_t)(i0 + ty * 8 + i);
    float* po = s + ((size_t)b * NN + row) * NN + j0 + tx * 8;
    *(float4*)po = make_float4(acc[i][0], acc[i][1], acc[i][2], acc[i][3]);
    *(float4*)(po + 4) = make_float4(acc[i][4], acc[i][5], acc[i][6], acc[i][7]);
  }
}

// ---------------------------------------------------------------------------
// Kernel 2: in-place row softmax; emits diagonal prob.
// ---------------------------------------------------------------------------
__device__ inline float pick4(float4 v, int j) {
  return j == 0 ? v.x : (j == 1 ? v.y : (j == 2 ? v.z : v.w));
}

__global__ __launch_bounds__(256) void softmax_rows(float* __restrict__ s,
                                                    float* __restrict__ diag) {
  const int bi = blockIdx.x;
  const int irow = bi & (NN - 1);
  const int t = threadIdx.x;
  float4* rowp = (float4*)(s + (size_t)bi * NN);
  float4 v0 = rowp[t];
  float4 v1 = rowp[256 + t];

  __shared__ float red[4];
  float m = fmaxf(fmaxf(fmaxf(v0.x, v0.y), fmaxf(v0.z, v0.w)),
                  fmaxf(fmaxf(v1.x, v1.y), fmaxf(v1.z, v1.w)));
#pragma unroll
  for (int off = 32; off; off >>= 1) m = fmaxf(m, __shfl_xor(m, off));
  if ((t & 63) == 0) red[t >> 6] = m;
  __syncthreads();
  m = fmaxf(fmaxf(red[0], red[1]), fmaxf(red[2], red[3]));
  __syncthreads();

  float4 e0, e1;
  e0.x = expf(v0.x - m); e0.y = expf(v0.y - m);
  e0.z = expf(v0.z - m); e0.w = expf(v0.w - m);
  e1.x = expf(v1.x - m); e1.y = expf(v1.y - m);
  e1.z = expf(v1.z - m); e1.w = expf(v1.w - m);
  float sum = e0.x + e0.y + e0.z + e0.w + e1.x + e1.y + e1.z + e1.w;
#pragma unroll
  for (int off = 32; off; off >>= 1) sum += __shfl_xor(sum, off);
  if ((t & 63) == 0) red[t >> 6] = sum;
  __syncthreads();
  sum = red[0] + red[1] + red[2] + red[3];

  float inv = 1.0f / sum;
  float4 s0 = make_float4(e0.x * inv, e0.y * inv, e0.z * inv, e0.w * inv);
  float4 s1 = make_float4(e1.x * inv, e1.y * inv, e1.z * inv, e1.w * inv);
  rowp[t] = s0;
  rowp[256 + t] = s1;

  int c0 = t * 4;
  if (irow >= c0 && irow < c0 + 4) diag[bi] = pick4(s0, irow - c0);
  int c1 = 1024 + t * 4;
  if (irow >= c1 && irow < c1 + 4) diag[bi] = pick4(s1, irow - c1);
}

// ---------------------------------------------------------------------------
// Kernel 3: top-100 of diag per batch via bitonic sort of packed keys.
// ---------------------------------------------------------------------------
__global__ __launch_bounds__(1024) void topk_diag(const float* __restrict__ diag,
                                                  int* __restrict__ topidx) {
  const int b = blockIdx.x;
  const int t = threadIdx.x;
  __shared__ unsigned long long key[NN];
  __shared__ int idxs[KK];

#pragma unroll
  for (int sIt = 0; sIt < 2; ++sIt) {
    int i = t + sIt * 1024;
    unsigned int vb = __float_as_uint(diag[b * NN + i]);
    key[i] = ((unsigned long long)vb << 32) | (unsigned int)(NN - 1 - i);
  }
  __syncthreads();

  for (int kstep = 2; kstep <= NN; kstep <<= 1) {
    for (int j = kstep >> 1; j > 0; j >>= 1) {
      int i = ((t & ~(j - 1)) << 1) | (t & (j - 1));
      int l = i | j;
      unsigned long long a = key[i];
      unsigned long long c = key[l];
      bool desc = ((i & kstep) == 0);
      if (desc ? (a < c) : (a > c)) { key[i] = c; key[l] = a; }
      __syncthreads();
    }
  }

  if (t < KK) idxs[t] = NN - 1 - (int)(unsigned int)(key[t] & 0xFFFFFFFFu);
  __syncthreads();
  if (t < KK) {
    int myidx = idxs[t];
    int rank = 0;
#pragma unroll 4
    for (int j = 0; j < KK; ++j) rank += (idxs[j] < myidx) ? 1 : 0;
    topidx[b * KK + rank] = myidx;
  }
}

// ---------------------------------------------------------------------------
// Kernel 4 (v2): one wave per (batch, row-of-rel). 800 blocks instead of 8.
// Lane l holds rel[i][l] and rel[i][l+64]; top-5 via 5 rounds of 64-lane
// key-max reduce. Key = (valbits<<32)|(99-j): max picks largest value, then
// smallest j (== lax.top_k first-occurrence tie-break). Values are >= 0 so
// float bits are order-preserving.
// ---------------------------------------------------------------------------
__global__ __launch_bounds__(64) void rel_topk(const float* __restrict__ s,
                                               const int* __restrict__ topidx,
                                               float* __restrict__ soi,
                                               int2* __restrict__ pairs) {
  const int b = blockIdx.y;
  const int i = blockIdx.x;  // 0..KK-1
  const int l = threadIdx.x;
  const int* tixb = topidx + b * KK;
  const int subj = tixb[i];
  const float* srow = s + ((size_t)b * NN + subj) * NN;

  const int j0 = l, j1 = l + 64;
  int c0 = tixb[j0];
  float v0 = (j0 == i) ? BIGV : srow[c0];
  unsigned long long k0 =
      ((unsigned long long)__float_as_uint(v0) << 32) | (unsigned int)(KK - 1 - j0);
  unsigned long long k1 = 0ull;
  if (j1 < KK) {
    int c1 = tixb[j1];
    float v1 = (j1 == i) ? BIGV : srow[c1];
    k1 = ((unsigned long long)__float_as_uint(v1) << 32) | (unsigned int)(KK - 1 - j1);
  }

  int sel[RR];
#pragma unroll
  for (int r = 0; r < RR; ++r) {
    unsigned long long best = k0 > k1 ? k0 : k1;
#pragma unroll
    for (int off = 32; off; off >>= 1) {
      unsigned long long o = __shfl_xor(best, off);
      if (o > best) best = o;
    }
    int js = KK - 1 - (int)(unsigned int)(best & 0xFFFFFFFFull);
    sel[r] = js;
    if (j0 == js) k0 = 0ull;  // mark taken (any real untaken j outranks 0)
    if (j1 == js) k1 = 0ull;
  }

  if (l == 0) {
#pragma unroll
    for (int a2 = 0; a2 < RR; ++a2)
#pragma unroll
      for (int b2 = a2 + 1; b2 < RR; ++b2)
        if (sel[b2] < sel[a2]) { int tmp = sel[a2]; sel[a2] = sel[b2]; sel[b2] = tmp; }
#pragma unroll
    for (int r = 0; r < RR; ++r) {
      int obj = tixb[sel[r]];
      size_t p = ((size_t)b * KK + i) * RR + r;
      soi[p * 3 + 0] = (float)b;
      soi[p * 3 + 1] = (float)subj;
      soi[p * 3 + 2] = (float)obj;
      pairs[p] = make_int2(subj, obj);
    }
  }
}

// ---------------------------------------------------------------------------
// Kernel 5: re = layernorm(q[b,subj] + q[b,obj]) over D=256. One wave per edge.
// ---------------------------------------------------------------------------
__global__ __launch_bounds__(64) void edge_ln(const float* __restrict__ q,
                                              const int2* __restrict__ pairs,
                                              float* __restrict__ re) {
  const int p = blockIdx.x;
  const int b = p / (KK * RR);
  const int l = threadIdx.x;
  int2 pr = pairs[p];
  const float4* qs = (const float4*)(q + ((size_t)b * NN + pr.x) * DD);
  const float4* qo = (const float4*)(q + ((size_t)b * NN + pr.y) * DD);
  float4 a = qs[l];
  float4 o = qo[l];
  a.x += o.x; a.y += o.y; a.z += o.z; a.w += o.w;
  float sum = a.x + a.y + a.z + a.w;
  float sq = a.x * a.x + a.y * a.y + a.z * a.z + a.w * a.w;
#pragma unroll
  for (int off = 32; off; off >>= 1) {
    sum += __shfl_xor(sum, off);
    sq += __shfl_xor(sq, off);
  }
  float mu = sum * (1.f / DD);
  float var = sq * (1.f / DD) - mu * mu;
  float rs = rsqrtf(var + LN_EPS);
  float4 r4 = make_float4((a.x - mu) * rs, (a.y - mu) * rs,
                          (a.z - mu) * rs, (a.w - mu) * rs);
  ((float4*)(re + (size_t)p * DD))[l] = r4;
}

// ---------------------------------------------------------------------------
extern "C" void kernel_launch(void* const* d_in, const int* in_sizes, int n_in,
                              void* d_out, int out_size, void* d_ws, size_t ws_size,
                              hipStream_t stream) {
  const float* q = (const float*)d_in[0];
  const float* k = (const float*)d_in[1];

  float* out = (float*)d_out;
  float* scores = out;                                    // B*N*N
  float* soi = out + (size_t)BB * NN * NN;                // B*K*R*3
  float* re = soi + (size_t)BB * KK * RR * 3;             // B*K*R*D

  char* ws = (char*)d_ws;
  float* diag = (float*)ws;                               // 64 KiB
  int* topidx = (int*)(ws + (size_t)BB * NN * 4);
  int2* pairs = (int2*)(ws + (size_t)BB * NN * 4 + (size_t)BB * KK * 4);
  const size_t small_end = 128 * 1024;                    // small region rounded up
  const size_t plane = (size_t)BB * NN * DD * 2;          // 8 MiB per bf16 plane
  const bool use_mfma = ws_size >= small_end + 4 * plane;

  if (use_mfma) {
    unsigned short* qhi = (unsigned short*)(ws + small_end);
    unsigned short* qlo = (unsigned short*)(ws + small_end + plane);
    unsigned short* khi = (unsigned short*)(ws + small_end + 2 * plane);
    unsigned short* klo = (unsigned short*)(ws + small_end + 3 * plane);
    split_bf16<<<dim3(1024, 2), 256, 0, stream>>>(q, k, (ushort4*)qhi, (ushort4*)qlo,
                                                  (ushort4*)khi, (ushort4*)klo);
    gemm_mfma_split<<<dim3(NN / 128, NN / 128, BB), 256, 0, stream>>>(qhi, qlo, khi, klo,
                                                                      scores);
  } else {
    gemm_logits<<<dim3(NN / 128, NN / 128, BB), 256, 0, stream>>>(q, k, scores);
  }
  softmax_rows<<<dim3(BB * NN), 256, 0, stream>>>(scores, diag);
  topk_diag<<<dim3(BB), 1024, 0, stream>>>(diag, topidx);
  rel_topk<<<dim3(KK, BB), 64, 0, stream>>>(scores, topidx, soi, pairs);
  edge_ln<<<dim3(BB * KK * RR), 64, 0, stream>>>(q, pairs, re);
}

// Round 2
// 281.053 us; speedup vs baseline: 1.1604x; 1.0023x over previous
//
#include <hip/hip_runtime.h>
#include <math.h>

#define BB 8
#define NN 2048
#define DD 256
#define KK 100
#define RR 5
#define BIGV 1000000000.0f
#define LN_EPS 1e-5f

typedef __attribute__((ext_vector_type(8))) short short8;
typedef __attribute__((ext_vector_type(4))) float floatx4;

// ---------------------------------------------------------------------------
// bf16 helpers (manual RNE to avoid header API variance)
// ---------------------------------------------------------------------------
__device__ static inline unsigned short f2bf_rne(float x) {
  unsigned int u = __float_as_uint(x);
  unsigned int r = (u + 0x7FFFu + ((u >> 16) & 1u)) >> 16;
  return (unsigned short)r;
}
__device__ static inline float bf2f(unsigned short h) {
  return __uint_as_float(((unsigned int)h) << 16);
}

__device__ static inline void gl_lds16(const unsigned short* g, unsigned short* l) {
  __builtin_amdgcn_global_load_lds(
      (const __attribute__((address_space(1))) unsigned int*)(g),
      (__attribute__((address_space(3))) unsigned int*)(l), 16, 0, 0);
}

// ---------------------------------------------------------------------------
// Kernel 0: split q,k (fp32) into bf16 hi/lo planes. hi = RNE(x), lo = RNE(x-hi).
// ---------------------------------------------------------------------------
__global__ __launch_bounds__(256) void split_bf16(const float* __restrict__ q,
                                                  const float* __restrict__ k,
                                                  ushort4* __restrict__ qhi,
                                                  ushort4* __restrict__ qlo,
                                                  ushort4* __restrict__ khi,
                                                  ushort4* __restrict__ klo) {
  const int n4 = BB * NN * DD / 4;
  const float4* src = (blockIdx.y == 0) ? (const float4*)q : (const float4*)k;
  ushort4* hi = blockIdx.y ? khi : qhi;
  ushort4* lo = blockIdx.y ? klo : qlo;
  for (int i = blockIdx.x * 256 + threadIdx.x; i < n4; i += gridDim.x * 256) {
    float4 v = src[i];
    ushort4 h, l;
    h.x = f2bf_rne(v.x); l.x = f2bf_rne(v.x - bf2f(h.x));
    h.y = f2bf_rne(v.y); l.y = f2bf_rne(v.y - bf2f(h.y));
    h.z = f2bf_rne(v.z); l.z = f2bf_rne(v.z - bf2f(h.z));
    h.w = f2bf_rne(v.w); l.w = f2bf_rne(v.w - bf2f(h.w));
    hi[i] = h; lo[i] = l;
  }
}

// ---------------------------------------------------------------------------
// Kernel 1: logits via MFMA with 3-term bf16 split.
// 128x128 tile per block, 4 waves (2x2 of 64x64), BK=32, 16x16x32 bf16 MFMA.
// Double-buffered LDS (2x32 KiB) + raw s_barrier + counted vmcnt(8) so
// stage t+1's global_load_lds stay in flight across step t's compute.
// XCD swizzle: 2048 blocks, XCD c <- batch c (4 MB of planes fits 4 MB L2).
// ---------------------------------------------------------------------------
__global__ __launch_bounds__(256) void gemm_mfma_split(
    const unsigned short* __restrict__ qhi, const unsigned short* __restrict__ qlo,
    const unsigned short* __restrict__ khi, const unsigned short* __restrict__ klo,
    float* __restrict__ s) {
  __shared__ unsigned short lds[2][4][8][512];  // 64 KiB, double-buffered

  // grid = (16,16,8) -> 2048 blocks, nwg % 8 == 0 so swizzle is bijective
  const int lid = blockIdx.x + ((blockIdx.y + (blockIdx.z << 4)) << 4);
  const int swz = ((lid & 7) << 8) + (lid >> 3);
  const int bx = swz & 15;
  const int by = (swz >> 4) & 15;
  const int b = swz >> 8;
  const int i0 = by * 128, j0 = bx * 128;

  const int t = threadIdx.x;
  const int w = t >> 6, L = t & 63;
  const int wx = w & 1, wy = w >> 1;
  const int q_ = L >> 4, m_ = L & 15;

  const size_t bofs = (size_t)b * NN * DD;
  const unsigned short* base;
  {
    const unsigned short* b0 = qhi + bofs;
    const unsigned short* b1 = qlo + bofs;
    const unsigned short* b2 = khi + bofs;
    const unsigned short* b3 = klo + bofs;
    base = (w == 0) ? b0 : (w == 1) ? b1 : (w == 2) ? b2 : b3;
  }
  const int rowbase = (w < 2 ? i0 : j0);
  // per-lane global base: row (rowbase + r*16 + m_), col (kb0 + q_*8)
  const unsigned short* gbase = base + (size_t)(rowbase + m_) * DD + q_ * 8;

  floatx4 acc[4][4];
#pragma unroll
  for (int i = 0; i < 4; ++i)
#pragma unroll
    for (int j = 0; j < 4; ++j) acc[i][j] = (floatx4){0.f, 0.f, 0.f, 0.f};

#define STAGE(buf, kb0)                                              \
  _Pragma("unroll") for (int r = 0; r < 8; ++r)                      \
      gl_lds16(gbase + (size_t)r * 16 * DD + (kb0), &lds[buf][w][r][0]);

  STAGE(0, 0);
  int cur = 0;
#pragma unroll
  for (int it = 0; it < 8; ++it) {
    if (it < 7) {
      STAGE(cur ^ 1, (it + 1) * 32);
      // wait only for stage `it`'s 8 loads; stage it+1's 8 stay in flight
      asm volatile("s_waitcnt vmcnt(8)" ::: "memory");
    } else {
      asm volatile("s_waitcnt vmcnt(0)" ::: "memory");
    }
    __builtin_amdgcn_s_barrier();

    short8 ah[4], al[4], bh[4], bl[4];
#pragma unroll
    for (int i = 0; i < 4; ++i) {
      ah[i] = *(const short8*)&lds[cur][0][wy * 4 + i][L * 8];
      al[i] = *(const short8*)&lds[cur][1][wy * 4 + i][L * 8];
      bh[i] = *(const short8*)&lds[cur][2][wx * 4 + i][L * 8];
      bl[i] = *(const short8*)&lds[cur][3][wx * 4 + i][L * 8];
    }
#pragma unroll
    for (int i = 0; i < 4; ++i)
#pragma unroll
      for (int j = 0; j < 4; ++j) {
        acc[i][j] = __builtin_amdgcn_mfma_f32_16x16x32_bf16(ah[i], bh[j], acc[i][j], 0, 0, 0);
        acc[i][j] = __builtin_amdgcn_mfma_f32_16x16x32_bf16(ah[i], bl[j], acc[i][j], 0, 0, 0);
        acc[i][j] = __builtin_amdgcn_mfma_f32_16x16x32_bf16(al[i], bh[j], acc[i][j], 0, 0, 0);
      }
    // all ds_reads of buf[cur] were consumed by the MFMAs above (lgkmcnt
    // inserted by compiler), so after this barrier buf[cur] may be restaged.
    __builtin_amdgcn_s_barrier();
    cur ^= 1;
  }
#undef STAGE

  // C/D layout (m89-verified): col = lane&15, row = (lane>>4)*4 + reg
#pragma unroll
  for (int i = 0; i < 4; ++i)
#pragma unroll
    for (int j = 0; j < 4; ++j)
#pragma unroll
      for (int r = 0; r < 4; ++r) {
        int row = i0 + wy * 64 + i * 16 + q_ * 4 + r;
        int col = j0 + wx * 64 + j * 16 + m_;
        s[((size_t)b * NN + row) * NN + col] = acc[i][j][r];
      }
}

// ---------------------------------------------------------------------------
// Kernel 1-fallback: fp32 vector GEMM (used only if ws too small for splits).
// ---------------------------------------------------------------------------
__global__ __launch_bounds__(256) void gemm_logits(const float* __restrict__ q,
                                                   const float* __restrict__ k,
                                                   float* __restrict__ s) {
  __shared__ float As[32][132];
  __shared__ float Bs[32][132];
  const int b = blockIdx.z;
  const int i0 = blockIdx.y * 128;
  const int j0 = blockIdx.x * 128;
  const int t = threadIdx.x;
  const int tx = t & 15;
  const int ty = t >> 4;
  const float* qb = q + (size_t)b * NN * DD;
  const float* kb = k + (size_t)b * NN * DD;

  float acc[8][8];
#pragma unroll
  for (int i = 0; i < 8; ++i)
#pragma unroll
    for (int j = 0; j < 8; ++j) acc[i][j] = 0.f;

  for (int kb0 = 0; kb0 < DD; kb0 += 32) {
#pragma unroll
    for (int l = 0; l < 4; ++l) {
      int f = l * 256 + t;
      int row = f >> 3;
      int c4 = (f & 7) * 4;
      float4 va = *(const float4*)(qb + (size_t)(i0 + row) * DD + kb0 + c4);
      float4 vb = *(const float4*)(kb + (size_t)(j0 + row) * DD + kb0 + c4);
      As[c4 + 0][row] = va.x; As[c4 + 1][row] = va.y;
      As[c4 + 2][row] = va.z; As[c4 + 3][row] = va.w;
      Bs[c4 + 0][row] = vb.x; Bs[c4 + 1][row] = vb.y;
      Bs[c4 + 2][row] = vb.z; Bs[c4 + 3][row] = vb.w;
    }
    __syncthreads();
#pragma unroll
    for (int kk = 0; kk < 32; ++kk) {
      float a[8], bv[8];
      *(float4*)&a[0] = *(const float4*)&As[kk][ty * 8];
      *(float4*)&a[4] = *(const float4*)&As[kk][ty * 8 + 4];
      *(float4*)&bv[0] = *(const float4*)&Bs[kk][tx * 8];
      *(float4*)&bv[4] = *(const float4*)&Bs[kk][tx * 8 + 4];
#pragma unroll
      for (int i = 0; i < 8; ++i)
#pragma unroll
        for (int j = 0; j < 8; ++j) acc[i][j] += a[i] * bv[j];
    }
    __syncthreads();
  }

#pragma unroll
  for (int i = 0; i < 8; ++i) {
    size_t row = (size_t)(i0 + ty * 8 + i);
    float* po = s + ((size_t)b * NN + row) * NN + j0 + tx * 8;
    *(float4*)po = make_float4(acc[i][0], acc[i][1], acc[i][2], acc[i][3]);
    *(float4*)(po + 4) = make_float4(acc[i][4], acc[i][5], acc[i][6], acc[i][7]);
  }
}

// ---------------------------------------------------------------------------
// Kernel 2: in-place row softmax; emits diagonal prob.
// ---------------------------------------------------------------------------
__device__ inline float pick4(float4 v, int j) {
  return j == 0 ? v.x : (j == 1 ? v.y : (j == 2 ? v.z : v.w));
}

__global__ __launch_bounds__(256) void softmax_rows(float* __restrict__ s,
                                                    float* __restrict__ diag) {
  const int bi = blockIdx.x;
  const int irow = bi & (NN - 1);
  const int t = threadIdx.x;
  float4* rowp = (float4*)(s + (size_t)bi * NN);
  float4 v0 = rowp[t];
  float4 v1 = rowp[256 + t];

  __shared__ float red[4];
  float m = fmaxf(fmaxf(fmaxf(v0.x, v0.y), fmaxf(v0.z, v0.w)),
                  fmaxf(fmaxf(v1.x, v1.y), fmaxf(v1.z, v1.w)));
#pragma unroll
  for (int off = 32; off; off >>= 1) m = fmaxf(m, __shfl_xor(m, off));
  if ((t & 63) == 0) red[t >> 6] = m;
  __syncthreads();
  m = fmaxf(fmaxf(red[0], red[1]), fmaxf(red[2], red[3]));
  __syncthreads();

  float4 e0, e1;
  e0.x = expf(v0.x - m); e0.y = expf(v0.y - m);
  e0.z = expf(v0.z - m); e0.w = expf(v0.w - m);
  e1.x = expf(v1.x - m); e1.y = expf(v1.y - m);
  e1.z = expf(v1.z - m); e1.w = expf(v1.w - m);
  float sum = e0.x + e0.y + e0.z + e0.w + e1.x + e1.y + e1.z + e1.w;
#pragma unroll
  for (int off = 32; off; off >>= 1) sum += __shfl_xor(sum, off);
  if ((t & 63) == 0) red[t >> 6] = sum;
  __syncthreads();
  sum = red[0] + red[1] + red[2] + red[3];

  float inv = 1.0f / sum;
  float4 s0 = make_float4(e0.x * inv, e0.y * inv, e0.z * inv, e0.w * inv);
  float4 s1 = make_float4(e1.x * inv, e1.y * inv, e1.z * inv, e1.w * inv);
  rowp[t] = s0;
  rowp[256 + t] = s1;

  int c0 = t * 4;
  if (irow >= c0 && irow < c0 + 4) diag[bi] = pick4(s0, irow - c0);
  int c1 = 1024 + t * 4;
  if (irow >= c1 && irow < c1 + 4) diag[bi] = pick4(s1, irow - c1);
}

// ---------------------------------------------------------------------------
// Kernel 3a (v2): top-100 selection by rank instead of bitonic sort.
// key = (valbits<<32)|(NN-1-i) — identical ordering/tie-break to the old
// bitonic version (diag >= 0 so float bits are order-preserving; keys unique
// so exactly KK elements have rank < KK).
// Grid (16 chunks, 8 batches): block stages all 2048 keys in LDS (16 KiB);
// 2 threads per element, each scans 1024 keys (broadcast ds_read_b64 —
// all lanes of a wave read the same address, conflict-free).
// ---------------------------------------------------------------------------
__global__ __launch_bounds__(256) void topk_rank(const float* __restrict__ diag,
                                                 unsigned char* __restrict__ flags) {
  const int b = blockIdx.y;
  const int c = blockIdx.x;   // chunk of 128 elements
  const int t = threadIdx.x;  // 0..255
  __shared__ unsigned long long key[NN];
  __shared__ unsigned short partial[256];

#pragma unroll
  for (int sIt = 0; sIt < 8; ++sIt) {
    int i = t + sIt * 256;
    unsigned int vb = __float_as_uint(diag[b * NN + i]);
    key[i] = ((unsigned long long)vb << 32) | (unsigned int)(NN - 1 - i);
  }
  __syncthreads();

  const int e = c * 128 + (t & 127);
  const int base = (t >> 7) * 1024;  // waves 0,1 scan low half; 2,3 high half
  const unsigned long long my = key[e];
  int r = 0;
#pragma unroll 8
  for (int j = 0; j < 1024; ++j) r += (key[base + j] > my) ? 1 : 0;
  partial[t] = (unsigned short)r;
  __syncthreads();

  if (t < 128) {
    int rank = (int)partial[t] + (int)partial[t + 128];
    flags[b * NN + e] = (rank < KK) ? 1 : 0;
  }
}

// ---------------------------------------------------------------------------
// Kernel 3b: compact flags -> topidx sorted ascending by index, via per-wave
// ballot + popcount prefix (exactly KK flags are set per batch).
// ---------------------------------------------------------------------------
__global__ __launch_bounds__(1024) void topk_compact(const unsigned char* __restrict__ flags,
                                                     int* __restrict__ topidx) {
  const int b = blockIdx.x;
  const int t = threadIdx.x;
  __shared__ unsigned long long mask[32];
  const bool f0 = flags[b * NN + t] != 0;
  const bool f1 = flags[b * NN + t + 1024] != 0;
  const unsigned long long m0 = __ballot(f0);
  const unsigned long long m1 = __ballot(f1);
  const int w = t >> 6, l = t & 63;
  if (l == 0) { mask[w] = m0; mask[16 + w] = m1; }
  __syncthreads();
  if (f0) {
    int pos = __popcll(m0 & ((1ull << l) - 1ull));
    for (int j = 0; j < w; ++j) pos += __popcll(mask[j]);
    topidx[b * KK + pos] = t;
  }
  if (f1) {
    int pos = __popcll(m1 & ((1ull << l) - 1ull));
    for (int j = 0; j < 16 + w; ++j) pos += __popcll(mask[j]);
    topidx[b * KK + pos] = t + 1024;
  }
}

// ---------------------------------------------------------------------------
// Kernel 4: one wave per (batch, row-of-rel). Lane l holds rel[i][l] and
// rel[i][l+64]; top-5 via 5 rounds of 64-lane key-max reduce.
// ---------------------------------------------------------------------------
__global__ __launch_bounds__(64) void rel_topk(const float* __restrict__ s,
                                               const int* __restrict__ topidx,
                                               float* __restrict__ soi,
                                               int2* __restrict__ pairs) {
  const int b = blockIdx.y;
  const int i = blockIdx.x;  // 0..KK-1
  const int l = threadIdx.x;
  const int* tixb = topidx + b * KK;
  const int subj = tixb[i];
  const float* srow = s + ((size_t)b * NN + subj) * NN;

  const int j0 = l, j1 = l + 64;
  int c0 = tixb[j0];
  float v0 = (j0 == i) ? BIGV : srow[c0];
  unsigned long long k0 =
      ((unsigned long long)__float_as_uint(v0) << 32) | (unsigned int)(KK - 1 - j0);
  unsigned long long k1 = 0ull;
  if (j1 < KK) {
    int c1 = tixb[j1];
    float v1 = (j1 == i) ? BIGV : srow[c1];
    k1 = ((unsigned long long)__float_as_uint(v1) << 32) | (unsigned int)(KK - 1 - j1);
  }

  int sel[RR];
#pragma unroll
  for (int r = 0; r < RR; ++r) {
    unsigned long long best = k0 > k1 ? k0 : k1;
#pragma unroll
    for (int off = 32; off; off >>= 1) {
      unsigned long long o = __shfl_xor(best, off);
      if (o > best) best = o;
    }
    int js = KK - 1 - (int)(unsigned int)(best & 0xFFFFFFFFull);
    sel[r] = js;
    if (j0 == js) k0 = 0ull;  // mark taken (any real untaken j outranks 0)
    if (j1 == js) k1 = 0ull;
  }

  if (l == 0) {
#pragma unroll
    for (int a2 = 0; a2 < RR; ++a2)
#pragma unroll
      for (int b2 = a2 + 1; b2 < RR; ++b2)
        if (sel[b2] < sel[a2]) { int tmp = sel[a2]; sel[a2] = sel[b2]; sel[b2] = tmp; }
#pragma unroll
    for (int r = 0; r < RR; ++r) {
      int obj = tixb[sel[r]];
      size_t p = ((size_t)b * KK + i) * RR + r;
      soi[p * 3 + 0] = (float)b;
      soi[p * 3 + 1] = (float)subj;
      soi[p * 3 + 2] = (float)obj;
      pairs[p] = make_int2(subj, obj);
    }
  }
}

// ---------------------------------------------------------------------------
// Kernel 5: re = layernorm(q[b,subj] + q[b,obj]) over D=256. One wave per edge.
// ---------------------------------------------------------------------------
__global__ __launch_bounds__(64) void edge_ln(const float* __restrict__ q,
                                              const int2* __restrict__ pairs,
                                              float* __restrict__ re) {
  const int p = blockIdx.x;
  const int b = p / (KK * RR);
  const int l = threadIdx.x;
  int2 pr = pairs[p];
  const float4* qs = (const float4*)(q + ((size_t)b * NN + pr.x) * DD);
  const float4* qo = (const float4*)(q + ((size_t)b * NN + pr.y) * DD);
  float4 a = qs[l];
  float4 o = qo[l];
  a.x += o.x; a.y += o.y; a.z += o.z; a.w += o.w;
  float sum = a.x + a.y + a.z + a.w;
  float sq = a.x * a.x + a.y * a.y + a.z * a.z + a.w * a.w;
#pragma unroll
  for (int off = 32; off; off >>= 1) {
    sum += __shfl_xor(sum, off);
    sq += __shfl_xor(sq, off);
  }
  float mu = sum * (1.f / DD);
  float var = sq * (1.f / DD) - mu * mu;
  float rs = rsqrtf(var + LN_EPS);
  float4 r4 = make_float4((a.x - mu) * rs, (a.y - mu) * rs,
                          (a.z - mu) * rs, (a.w - mu) * rs);
  ((float4*)(re + (size_t)p * DD))[l] = r4;
}

// ---------------------------------------------------------------------------
extern "C" void kernel_launch(void* const* d_in, const int* in_sizes, int n_in,
                              void* d_out, int out_size, void* d_ws, size_t ws_size,
                              hipStream_t stream) {
  const float* q = (const float*)d_in[0];
  const float* k = (const float*)d_in[1];

  float* out = (float*)d_out;
  float* scores = out;                                    // B*N*N
  float* soi = out + (size_t)BB * NN * NN;                // B*K*R*3
  float* re = soi + (size_t)BB * KK * RR * 3;             // B*K*R*D

  char* ws = (char*)d_ws;
  float* diag = (float*)ws;                               // 64 KiB
  int* topidx = (int*)(ws + (size_t)BB * NN * 4);
  int2* pairs = (int2*)(ws + (size_t)BB * NN * 4 + (size_t)BB * KK * 4);
  unsigned char* flags =
      (unsigned char*)(ws + (size_t)BB * NN * 4 + (size_t)BB * KK * 4 +
                       (size_t)BB * KK * RR * 8);         // 16 KiB, ends < 128 KiB
  const size_t small_end = 128 * 1024;                    // small region rounded up
  const size_t plane = (size_t)BB * NN * DD * 2;          // 8 MiB per bf16 plane
  const bool use_mfma = ws_size >= small_end + 4 * plane;

  if (use_mfma) {
    unsigned short* qhi = (unsigned short*)(ws + small_end);
    unsigned short* qlo = (unsigned short*)(ws + small_end + plane);
    unsigned short* khi = (unsigned short*)(ws + small_end + 2 * plane);
    unsigned short* klo = (unsigned short*)(ws + small_end + 3 * plane);
    split_bf16<<<dim3(1024, 2), 256, 0, stream>>>(q, k, (ushort4*)qhi, (ushort4*)qlo,
                                                  (ushort4*)khi, (ushort4*)klo);
    gemm_mfma_split<<<dim3(NN / 128, NN / 128, BB), 256, 0, stream>>>(qhi, qlo, khi, klo,
                                                                      scores);
  } else {
    gemm_logits<<<dim3(NN / 128, NN / 128, BB), 256, 0, stream>>>(q, k, scores);
  }
  softmax_rows<<<dim3(BB * NN), 256, 0, stream>>>(scores, diag);
  topk_rank<<<dim3(16, BB), 256, 0, stream>>>(diag, flags);
  topk_compact<<<dim3(BB), 1024, 0, stream>>>(flags, topidx);
  rel_topk<<<dim3(KK, BB), 64, 0, stream>>>(scores, topidx, soi, pairs);
  edge_ln<<<dim3(BB * KK * RR), 64, 0, stream>>>(q, pairs, re);
}